// Round 16
// baseline (87.937 us; speedup 1.0000x reference)
//
#include <hip/hip_runtime.h>
#include <hip/hip_bf16.h>
#include <cstdint>

typedef __attribute__((ext_vector_type(8))) short short8;
typedef __attribute__((ext_vector_type(4))) float f32x4;
typedef __attribute__((ext_vector_type(16))) float f32x16;

#define BDIM 32
#define CDIM 2048
#define NPIX 196    // 14*14
#define HIN 14
#define N2 784      // 28*28
#define W2 28
#define KDIM 113
#define KC 112
#define NCLS 200
#define NBX 14      // col-blocks per image (2 output rows each)
#define BNC 56      // output cols per block
#define NSTEP 64    // 2048/32
#define PST 224     // staged plane stride (196 + 28 pad)
#define GST 200     // Gram per-type stride
#define RDST 68     // RDs row stride (f32)
#define SSTB 60     // Ssb row stride (ushort)

// ---------------- K_stage: merged k_prep (blocks 512..639) + k_xt (blocks 0..511) ----------------
// k_xt role: async-split double-buffered transpose + Gram (verified r14/r15).
// k_prep role: concepts (+cfcw row 113) -> bf16 32x32x16 A-fragment order + csq (512-thr variant).
__global__ __launch_bounds__(512, 2) void k_stage(
    const float* __restrict__ x,
    const float* __restrict__ concepts,
    const float* __restrict__ cfcw,
    ushort* __restrict__ cbf,
    float* __restrict__ csq,
    ushort* __restrict__ xt,
    float* __restrict__ Gpart) {
  __shared__ float P[2][32 * PST];     // 57.3 KB; reused as Gw after the loop
  __shared__ float r8[8];
  const int wgid = blockIdx.x;
  const int tid = threadIdx.x;
  const int lane = tid & 63, wv = tid >> 6;

  if (wgid >= 512) {
    // ---- k_prep role ----
    const int k = wgid - 512;
    const int kt = k >> 5, row = k & 31;
    float s = 0.f;
    for (int c = tid; c < CDIM; c += 512) {
      float v = (k < KDIM) ? concepts[(size_t)k * CDIM + c] : (k == KDIM ? cfcw[c] : 0.f);
      __hip_bfloat16 h = __float2bfloat16(v);
      int st = c >> 5, it = (c >> 4) & 1, g2 = (c >> 3) & 1, j = c & 7;
      cbf[(((size_t)st * 4 + kt) * 2 + it) * 512 + (g2 * 32 + row) * 8 + j] = __bfloat16_as_ushort(h);
      float vb = __bfloat162float(h);
      s = fmaf(vb, vb, s);
    }
#pragma unroll
    for (int off = 32; off > 0; off >>= 1) s += __shfl_down(s, off, 64);
    if (lane == 0) r8[wv] = s;
    __syncthreads();
    if (tid == 0) {
      float tot = 0.f;
#pragma unroll
      for (int i = 0; i < 8; ++i) tot += r8[i];
      csq[k] = tot;
    }
    return;
  }

  // ---- k_xt role ----
  const int sg = wgid & 15, b = wgid >> 4;
  const int chg = tid >> 4, seg = tid & 15;
  const int p0 = seg * 13;

  const int c0a = tid / 49,           pq0 = tid - c0a * 49;
  const int c1a = (tid + 512) / 49,   pq1 = (tid + 512) - c1a * 49;
  const int c2a = (tid + 1024) / 49,  pq2 = (tid + 1024) - c2a * 49;
  const int c3a = (tid + 1536) / 49,  pq3 = (tid + 1536) - c3a * 49;  // tid<32 only

  for (int z = tid; z < 2 * 32 * 28; z += 512) {
    int buf = z / 896, r = z - buf * 896;
    int c = r / 28, j = r - c * 28;
    P[buf][c * PST + 196 + j] = 0.f;
  }

  float g[13][5];
#pragma unroll
  for (int p = 0; p < 13; ++p)
#pragma unroll
    for (int t = 0; t < 5; ++t) g[p][t] = 0.f;

  float4 q0, q1, q2, q3 = {0.f, 0.f, 0.f, 0.f};
  auto LOADQ = [&](int s) {
    const float4* src = (const float4*)(x + ((size_t)b * CDIM + s * 32) * NPIX);
    q0 = src[tid]; q1 = src[tid + 512]; q2 = src[tid + 1024];
    if (tid < 32) q3 = src[tid + 1536];
  };
  auto WRITEQ = [&](int buf) {
    float* Pb = P[buf];
    *(float4*)&Pb[c0a * PST + 4 * pq0] = q0;
    *(float4*)&Pb[c1a * PST + 4 * pq1] = q1;
    *(float4*)&Pb[c2a * PST + 4 * pq2] = q2;
    if (tid < 32) *(float4*)&Pb[c3a * PST + 4 * pq3] = q3;
  };

  LOADQ(sg * 4);
  WRITEQ(0);
  __syncthreads();

  for (int si = 0; si < 4; ++si) {
    const int s = sg * 4 + si;
    const int cur = si & 1;
    if (si < 3) LOADQ(s + 1);
#pragma unroll
    for (int pass = 0; pass < 2; ++pass) {
      int slot = tid + pass * 512;
      if (slot < 896) {
        int t = slot >> 7, r = slot & 127;
        int it = r >> 6, l = r & 63;
        int pxp = t * 32 + (l & 31);
        int row = pxp >> 4, col = pxp & 15;
        int c0 = it * 16 + (l >> 5) * 8;
        uint uu[4];
        if (col < 14) {
          int px = row * HIN + col;
#pragma unroll
          for (int p = 0; p < 4; ++p) {
            float v0 = P[cur][(c0 + 2 * p) * PST + px];
            float v1 = P[cur][(c0 + 2 * p + 1) * PST + px];
            uu[p] = (uint)__bfloat16_as_ushort(__float2bfloat16(v0)) |
                    ((uint)__bfloat16_as_ushort(__float2bfloat16(v1)) << 16);
          }
        } else {
          uu[0] = uu[1] = uu[2] = uu[3] = 0u;
        }
        uint4 pk; pk.x = uu[0]; pk.y = uu[1]; pk.z = uu[2]; pk.w = uu[3];
        *(uint4*)&xt[((((size_t)b * 7 + t) * 64 + s) * 1024) + it * 512 + (size_t)l * 8] = pk;
      }
    }
    {
      float xv[28];
      const float* Pr = &P[cur][chg * PST];
#pragma unroll
      for (int i = 0; i < 7; ++i) *(float4*)&xv[4 * i] = *(const float4*)&Pr[p0 + 4 * i];
#pragma unroll
      for (int p = 0; p < 13; ++p) {
        float a = xv[p];
        g[p][0] = fmaf(a, a, g[p][0]);
        g[p][1] = fmaf(a, xv[p + 1], g[p][1]);
        g[p][2] = fmaf(a, xv[p + 13], g[p][2]);
        g[p][3] = fmaf(a, xv[p + 14], g[p][3]);
        g[p][4] = fmaf(a, xv[p + 15], g[p][4]);
      }
    }
    if (si < 3) WRITEQ((si + 1) & 1);
    __syncthreads();
  }

  // ---- Gram reduce: reuse P storage as Gw[8*16*65] ----
  float* Gw = &P[0][0];
#pragma unroll
  for (int p = 0; p < 13; ++p)
#pragma unroll
    for (int t = 0; t < 5; ++t) {
      float v = g[p][t];
      v += __shfl_xor(v, 16, 64);
      v += __shfl_xor(v, 32, 64);
      g[p][t] = v;
    }
  if (lane < 16) {
#pragma unroll
    for (int p = 0; p < 13; ++p)
#pragma unroll
      for (int t = 0; t < 5; ++t) Gw[((size_t)wv * 16 + lane) * 65 + p * 5 + t] = g[p][t];
  }
  __syncthreads();
#pragma unroll
  for (int it = 0; it < 2; ++it) {
    int slot = tid + it * 512;
    if (slot < 16 * 65) {
      int sseg = slot / 65, i = slot - sseg * 65;
      float v = 0.f;
#pragma unroll
      for (int ww = 0; ww < 8; ++ww) v += Gw[((size_t)ww * 16 + sseg) * 65 + i];
      int pl = i / 5, ty = i - pl * 5;
      int px = sseg * 13 + pl;
      if (px < NPIX)
        Gpart[((size_t)b * 16 + sg) * (5 * GST) + ty * GST + px] = v;
    }
  }
}

// ---------------- K_gemm3: 32x32x16 barrier-free MFMA, 4-deep prefetch, inline Gram reduce ----
__global__ __launch_bounds__(256, 3) void k_gemm3(
    const ushort* __restrict__ xt,
    const ushort* __restrict__ cbf,
    const float* __restrict__ Gpart,   // [32][16][5*GST] partials (reduced inline)
    const float* __restrict__ csq,
    float* __restrict__ attn_out,
    float* __restrict__ part)
{
  __shared__ float RDs[128 * RDST];      // 34.8 KB
  __shared__ ushort Ssb[KDIM * SSTB];    // 13.6 KB
  __shared__ float csq_s[KDIM];
  __shared__ float xsqs[BNC], projs2[BNC];

  const int tid = threadIdx.x;
  const int wgid = blockIdx.x;
  const int xcd = wgid & 7, slot = wgid >> 3;
  const int bq = slot / NBX, bx = slot - bq * NBX;
  const int b = xcd + 8 * bq;
  const int n0 = bx * BNC;
  const int lane = tid & 63, w = tid >> 6;   // wave w = k-rows 32w..32w+31

  int r0 = bx - 1; if (r0 < 0) r0 = 0; if (r0 > 11) r0 = 11;
  const int T0 = r0 >> 1;                    // window = px' tiles T0, T0+1

  if (tid < KDIM) csq_s[tid] = csq[tid];

  const ushort* abp = cbf + w * 1024 + lane * 8;                    // + s*4096 + it*512
  const ushort* xtb = xt + (((size_t)b * 7 + T0) << 16) + lane * 8; // + tt*65536 + s*1024 + it*512

  f32x16 acc[2];
#pragma unroll
  for (int tt = 0; tt < 2; ++tt)
#pragma unroll
    for (int r = 0; r < 16; ++r) acc[tt][r] = 0.f;

#define LOADSET(A_, B_, S_)                                              \
  do {                                                                   \
    const size_t so_ = (size_t)(S_) * 4096;                              \
    const size_t xo_ = (size_t)(S_) * 1024;                              \
    A_[0] = *(const uint4*)(abp + so_);                                  \
    A_[1] = *(const uint4*)(abp + so_ + 512);                            \
    B_[0][0] = *(const uint4*)(xtb + xo_);                               \
    B_[0][1] = *(const uint4*)(xtb + xo_ + 512);                         \
    B_[1][0] = *(const uint4*)(xtb + 65536 + xo_);                       \
    B_[1][1] = *(const uint4*)(xtb + 65536 + xo_ + 512);                 \
  } while (0)

#define COMPUTE(A_, B_)                                                  \
  do {                                                                   \
    _Pragma("unroll")                                                    \
    for (int it_ = 0; it_ < 2; ++it_) {                                  \
      short8 af_ = *(const short8*)&A_[it_];                             \
      acc[0] = __builtin_amdgcn_mfma_f32_32x32x16_bf16(                  \
          af_, *(const short8*)&B_[0][it_], acc[0], 0, 0, 0);            \
      acc[1] = __builtin_amdgcn_mfma_f32_32x32x16_bf16(                  \
          af_, *(const short8*)&B_[1][it_], acc[1], 0, 0, 0);            \
    }                                                                    \
  } while (0)

  // 4-deep named prefetch ring (no barriers -> counted vmcnt pipelining survives)
  uint4 aA[2], aB[2], aC[2], aD[2];
  uint4 bA[2][2], bB[2][2], bC[2][2], bD[2][2];
  LOADSET(aA, bA, 0);
  LOADSET(aB, bB, 1);
  LOADSET(aC, bC, 2);
  LOADSET(aD, bD, 3);
  for (int s = 0; s < NSTEP; s += 4) {
    COMPUTE(aA, bA); if (s + 4 < NSTEP) LOADSET(aA, bA, s + 4);
    COMPUTE(aB, bB); if (s + 5 < NSTEP) LOADSET(aB, bB, s + 5);
    COMPUTE(aC, bC); if (s + 6 < NSTEP) LOADSET(aC, bC, s + 6);
    COMPUTE(aD, bD); if (s + 7 < NSTEP) LOADSET(aD, bD, s + 7);
  }
#undef LOADSET
#undef COMPUTE

  // ---- RDs: 32x32 C/D layout col=lane&31, row=(r&3)+8*(r>>2)+4*(lane>>5) ----
#pragma unroll
  for (int tt = 0; tt < 2; ++tt)
#pragma unroll
    for (int r = 0; r < 16; ++r) {
      int row = w * 32 + (r & 3) + 8 * (r >> 2) + 4 * (lane >> 5);
      RDs[row * RDST + tt * 32 + (lane & 31)] = acc[tt][r];
    }
  __syncthreads();

  auto COLW = [&](int col, int& p1, int& p3, int& p1g, int& p3g,
                  float& w00, float& w01, float& w10, float& w11) {
    const int i2 = 2 * bx + (col >= 28 ? 1 : 0);
    const int j2 = col - (col >= 28 ? 28 : 0);
    float si = 0.5f * i2 - 0.25f, sj = 0.5f * j2 - 0.25f;
    float fif = floorf(si), fjf = floorf(sj);
    int ii = (int)fif, jj = (int)fjf;
    float fi = si - fif, fj = sj - fjf;
    int ia = ii < 0 ? 0 : ii; int ib = (ii + 1 > 13) ? 13 : ii + 1;
    int ja = jj < 0 ? 0 : jj; int jb = (jj + 1 > 13) ? 13 : jj + 1;
    w00 = (1.f - fi) * (1.f - fj); w01 = (1.f - fi) * fj;
    w10 = fi * (1.f - fj);         w11 = fi * fj;
    if (ib == ia) { w00 += w10; w01 += w11; w10 = 0.f; w11 = 0.f; }
    if (jb == ja) { w00 += w01; w10 += w11; w01 = 0.f; w11 = 0.f; }
    p1g = ia * HIN + ja; p3g = ib * HIN + ja;
    p1 = ia * 16 + ja - T0 * 32; p3 = ib * 16 + ja - T0 * 32;
  };

  // ---- xsq (Gram blend, inline 16-partial reduce — same order as old k_gred) + raw proj ----
  if (tid < BNC) {
    int p1, p3, p1g, p3g; float w00, w01, w10, w11;
    COLW(tid, p1, p3, p1g, p3g, w00, w01, w10, w11);
    const float* Gp = Gpart + (size_t)b * 16 * (5 * GST);
    auto GS = [&](int ty, int px) {
      float v = 0.f;
#pragma unroll
      for (int sg = 0; sg < 16; ++sg) v += Gp[(size_t)sg * (5 * GST) + ty * GST + px];
      return v;
    };
    // type mapping (r10-verified): 0=diag 1=right 2=down(Gy) 3=down-right? -> keep r13 usage:
    // Gd=ty0, Gr=ty1, Gy=ty2, Gv=ty3, Gx=ty4
    float xsq = w00 * w00 * GS(0, p1g) + w01 * w01 * GS(0, p1g + 1)
              + w10 * w10 * GS(0, p3g) + w11 * w11 * GS(0, p3g + 1)
              + 2.f * (w00 * w01 * GS(1, p1g) + w10 * w11 * GS(1, p3g)
                     + w00 * w10 * GS(3, p1g) + w01 * w11 * GS(3, p1g + 1)
                     + w00 * w11 * GS(4, p1g) + w01 * w10 * GS(2, p1g + 1));
    const float* rp = &RDs[113 * RDST];
    float pj = w00 * rp[p1] + w01 * rp[p1 + 1] + w10 * rp[p3] + w11 * rp[p3 + 1];
    xsqs[tid] = xsq; projs2[tid] = pj;
  }
  __syncthreads();

  // ---- dist (regs) -> quad softmax -> attn write (local rinv) + Ssb ----
  if (tid < BNC * 4) {
    const int col = tid >> 2, sub = tid & 3;
    int p1, p3, p1g, p3g; float w00, w01, w10, w11;
    COLW(col, p1, p3, p1g, p3g, w00, w01, w10, w11);
    const float xq = xsqs[col];
    float ev[29];
    float mx = -1e30f;
#pragma unroll
    for (int i = 0; i < 29; ++i) {
      int k = sub + 4 * i;
      if (k < KDIM) {
        const float* rk = &RDs[k * RDST];
        float dot = w00 * rk[p1] + w01 * rk[p1 + 1] + w10 * rk[p3] + w11 * rk[p3 + 1];
        float d2 = csq_s[k] + xq - 2.f * dot;
        float sv = -sqrtf(fmaxf(d2, 0.f));
        ev[i] = sv;
        mx = fmaxf(mx, sv);
      }
    }
    mx = fmaxf(mx, __shfl_xor(mx, 1, 64));
    mx = fmaxf(mx, __shfl_xor(mx, 2, 64));
    float ssum = 0.f;
#pragma unroll
    for (int i = 0; i < 29; ++i) {
      int k = sub + 4 * i;
      if (k < KDIM) {
        float e = __expf(ev[i] - mx);
        ev[i] = e;
        Ssb[k * SSTB + col] = __bfloat16_as_ushort(__float2bfloat16(e));
        ssum += e;
      }
    }
    ssum += __shfl_xor(ssum, 1, 64);
    ssum += __shfl_xor(ssum, 2, 64);
    const float rinv = 1.f / ssum;
    float* op = attn_out + (size_t)b * KDIM * N2 + n0 + col;
#pragma unroll
    for (int i = 0; i < 29; ++i) {
      int k = sub + 4 * i;
      if (k < KDIM) op[(size_t)k * N2] = ev[i] * rinv;
    }
    if (sub == 0) projs2[col] *= rinv;
  }
  __syncthreads();   // uniform barrier

  // ---- logit partials ----
  if (tid < KC * 2) {
    const int k = tid >> 1, s2 = tid & 1;
    float lg = 0.f;
    for (int c2 = s2; c2 < BNC; c2 += 2)
      lg = fmaf(__uint_as_float((uint)Ssb[k * SSTB + c2] << 16), projs2[c2], lg);
    lg += __shfl_xor(lg, 1, 64);
    if (s2 == 0) part[((size_t)b * NBX + bx) * KC + k] = lg;
  }
}

// ---------------- K_tmp (+sig fused) ----------------
__global__ __launch_bounds__(256) void k_tmp(
    const float* __restrict__ concepts, const float* __restrict__ part,
    const float* __restrict__ cfcb, float* __restrict__ cs_out,
    float* __restrict__ tmp) {
  __shared__ float cs_s[KC];
  const int b = blockIdx.y, cx = blockIdx.x;
  const int t = threadIdx.x;
  if (t < KC) {
    float l = cfcb[0];
#pragma unroll
    for (int q = 0; q < NBX; ++q) l += part[((size_t)b * NBX + q) * KC + t];
    float csv = 1.f / (1.f + __expf(-l));
    cs_s[t] = csv;
    if (cx == 0) cs_out[b * KC + t] = csv;
  }
  __syncthreads();
  const int c = cx * 256 + t;
  float a = 0.f;
#pragma unroll 8
  for (int k = 0; k < KC; ++k) a = fmaf(cs_s[k], concepts[(size_t)k * CDIM + c], a);
  tmp[(size_t)b * CDIM + c] = a;
}

// ---------------- K5b: preds ----------------
__global__ __launch_bounds__(256) void k_pred2(
    const float* __restrict__ labw, const float* __restrict__ labb,
    const float* __restrict__ tmp, float* __restrict__ preds) {
  const int w = blockIdx.x * 4 + (threadIdx.x >> 6);
  const int lane = threadIdx.x & 63;
  const int b = w / NCLS, cls = w % NCLS;
  if (b >= BDIM) return;
  const float* tr = tmp + (size_t)b * CDIM;
  const float* wr = labw + (size_t)cls * CDIM;
  float a = 0.f;
#pragma unroll
  for (int c0 = 0; c0 < CDIM; c0 += 256) {
    float4 t = *(const float4*)&tr[c0 + lane * 4];
    float4 v = *(const float4*)&wr[c0 + lane * 4];
    a += t.x * v.x + t.y * v.y + t.z * v.z + t.w * v.w;
  }
#pragma unroll
  for (int off = 32; off > 0; off >>= 1) a += __shfl_down(a, off, 64);
  if (lane == 0) preds[b * NCLS + cls] = a + labb[cls];
}

extern "C" void kernel_launch(void* const* d_in, const int* in_sizes, int n_in,
                              void* d_out, int out_size, void* d_ws, size_t ws_size,
                              hipStream_t stream) {
  const float* x        = (const float*)d_in[0];
  const float* concepts = (const float*)d_in[1];
  const float* cfcw     = (const float*)d_in[2];
  const float* cfcb     = (const float*)d_in[3];
  const float* labw     = (const float*)d_in[4];
  const float* labb     = (const float*)d_in[5];

  float* out    = (float*)d_out;
  float* sm_out = out;                                  // [32][113][784]
  float* cs_out = out + (size_t)BDIM * KDIM * N2;       // [32][112]
  float* pr_out = cs_out + (size_t)BDIM * KC;           // [32][200]

  char* ws = (char*)d_ws;
  float*  csq   = (float*)(ws + 0);          // 128 f32             512 B
  float*  part  = (float*)(ws + 512);        // 32*14*112 f32       200,704 B
  ushort* cbf   = (ushort*)(ws + 201216);    // 128*2048 bf16       524,288 B
  float*  tmp   = (float*)(ws + 725504);     // 32*2048 f32         262,144 B
  float*  Gpart = (float*)(ws + 987648);     // 32*16*1000 f32      2,048,000 B
  ushort* xt    = (ushort*)(ws + 3163648);   // 32*7*64*1024 bf16   29,360,128 B

  k_stage<<<dim3(640), dim3(512), 0, stream>>>(x, concepts, cfcw, cbf, csq, xt, Gpart);
  k_gemm3<<<dim3(448), dim3(256), 0, stream>>>(xt, cbf, Gpart, csq, sm_out, part);
  k_tmp  <<<dim3(CDIM / 256, BDIM), dim3(256), 0, stream>>>(concepts, part, cfcb, cs_out, tmp);
  k_pred2<<<dim3((BDIM * NCLS + 3) / 4), dim3(256), 0, stream>>>(labw, labb, tmp, pr_out);
}

// Round 17
// 79.632 us; speedup vs baseline: 1.1043x; 1.1043x over previous
//
#include <hip/hip_runtime.h>
#include <hip/hip_bf16.h>
#include <cstdint>

typedef __attribute__((ext_vector_type(8))) short short8;
typedef __attribute__((ext_vector_type(4))) float f32x4;
typedef __attribute__((ext_vector_type(16))) float f32x16;

#define BDIM 32
#define CDIM 2048
#define NPIX 196    // 14*14
#define HIN 14
#define N2 784      // 28*28
#define W2 28
#define KDIM 113
#define KC 112
#define NCLS 200
#define NBX 14      // col-blocks per image (2 output rows each)
#define BNC 56      // output cols per block
#define NSTEP 64    // 2048/32
#define PST 224     // staged plane stride (196 + 28 pad)
#define GST 200     // Gram per-type stride
#define RDST 68     // RDs row stride (f32)
#define SSTB 60     // Ssb row stride (ushort)

// ---------------- K_stage: merged k_prep (blocks 512..639) + k_xt (blocks 0..511) ----------------
__global__ __launch_bounds__(512, 2) void k_stage(
    const float* __restrict__ x,
    const float* __restrict__ concepts,
    const float* __restrict__ cfcw,
    ushort* __restrict__ cbf,
    float* __restrict__ csq,
    ushort* __restrict__ xt,
    float* __restrict__ Gpart) {
  __shared__ float P[2][32 * PST];     // 57.3 KB; reused as Gw after the loop
  __shared__ float r8[8];
  const int wgid = blockIdx.x;
  const int tid = threadIdx.x;
  const int lane = tid & 63, wv = tid >> 6;

  if (wgid >= 512) {
    // ---- k_prep role ----
    const int k = wgid - 512;
    const int kt = k >> 5, row = k & 31;
    float s = 0.f;
    for (int c = tid; c < CDIM; c += 512) {
      float v = (k < KDIM) ? concepts[(size_t)k * CDIM + c] : (k == KDIM ? cfcw[c] : 0.f);
      __hip_bfloat16 h = __float2bfloat16(v);
      int st = c >> 5, it = (c >> 4) & 1, g2 = (c >> 3) & 1, j = c & 7;
      cbf[(((size_t)st * 4 + kt) * 2 + it) * 512 + (g2 * 32 + row) * 8 + j] = __bfloat16_as_ushort(h);
      float vb = __bfloat162float(h);
      s = fmaf(vb, vb, s);
    }
#pragma unroll
    for (int off = 32; off > 0; off >>= 1) s += __shfl_down(s, off, 64);
    if (lane == 0) r8[wv] = s;
    __syncthreads();
    if (tid == 0) {
      float tot = 0.f;
#pragma unroll
      for (int i = 0; i < 8; ++i) tot += r8[i];
      csq[k] = tot;
    }
    return;
  }

  // ---- k_xt role ----
  const int sg = wgid & 15, b = wgid >> 4;
  const int chg = tid >> 4, seg = tid & 15;
  const int p0 = seg * 13;

  const int c0a = tid / 49,           pq0 = tid - c0a * 49;
  const int c1a = (tid + 512) / 49,   pq1 = (tid + 512) - c1a * 49;
  const int c2a = (tid + 1024) / 49,  pq2 = (tid + 1024) - c2a * 49;
  const int c3a = (tid + 1536) / 49,  pq3 = (tid + 1536) - c3a * 49;  // tid<32 only

  for (int z = tid; z < 2 * 32 * 28; z += 512) {
    int buf = z / 896, r = z - buf * 896;
    int c = r / 28, j = r - c * 28;
    P[buf][c * PST + 196 + j] = 0.f;
  }

  float g[13][5];
#pragma unroll
  for (int p = 0; p < 13; ++p)
#pragma unroll
    for (int t = 0; t < 5; ++t) g[p][t] = 0.f;

  float4 q0, q1, q2, q3 = {0.f, 0.f, 0.f, 0.f};
  auto LOADQ = [&](int s) {
    const float4* src = (const float4*)(x + ((size_t)b * CDIM + s * 32) * NPIX);
    q0 = src[tid]; q1 = src[tid + 512]; q2 = src[tid + 1024];
    if (tid < 32) q3 = src[tid + 1536];
  };
  auto WRITEQ = [&](int buf) {
    float* Pb = P[buf];
    *(float4*)&Pb[c0a * PST + 4 * pq0] = q0;
    *(float4*)&Pb[c1a * PST + 4 * pq1] = q1;
    *(float4*)&Pb[c2a * PST + 4 * pq2] = q2;
    if (tid < 32) *(float4*)&Pb[c3a * PST + 4 * pq3] = q3;
  };

  LOADQ(sg * 4);
  WRITEQ(0);
  __syncthreads();

  for (int si = 0; si < 4; ++si) {
    const int s = sg * 4 + si;
    const int cur = si & 1;
    if (si < 3) LOADQ(s + 1);
#pragma unroll
    for (int pass = 0; pass < 2; ++pass) {
      int slot = tid + pass * 512;
      if (slot < 896) {
        int t = slot >> 7, r = slot & 127;
        int it = r >> 6, l = r & 63;
        int pxp = t * 32 + (l & 31);
        int row = pxp >> 4, col = pxp & 15;
        int c0 = it * 16 + (l >> 5) * 8;
        uint uu[4];
        if (col < 14) {
          int px = row * HIN + col;
#pragma unroll
          for (int p = 0; p < 4; ++p) {
            float v0 = P[cur][(c0 + 2 * p) * PST + px];
            float v1 = P[cur][(c0 + 2 * p + 1) * PST + px];
            uu[p] = (uint)__bfloat16_as_ushort(__float2bfloat16(v0)) |
                    ((uint)__bfloat16_as_ushort(__float2bfloat16(v1)) << 16);
          }
        } else {
          uu[0] = uu[1] = uu[2] = uu[3] = 0u;
        }
        uint4 pk; pk.x = uu[0]; pk.y = uu[1]; pk.z = uu[2]; pk.w = uu[3];
        *(uint4*)&xt[((((size_t)b * 7 + t) * 64 + s) * 1024) + it * 512 + (size_t)l * 8] = pk;
      }
    }
    {
      float xv[28];
      const float* Pr = &P[cur][chg * PST];
#pragma unroll
      for (int i = 0; i < 7; ++i) *(float4*)&xv[4 * i] = *(const float4*)&Pr[p0 + 4 * i];
#pragma unroll
      for (int p = 0; p < 13; ++p) {
        float a = xv[p];
        g[p][0] = fmaf(a, a, g[p][0]);
        g[p][1] = fmaf(a, xv[p + 1], g[p][1]);
        g[p][2] = fmaf(a, xv[p + 13], g[p][2]);
        g[p][3] = fmaf(a, xv[p + 14], g[p][3]);
        g[p][4] = fmaf(a, xv[p + 15], g[p][4]);
      }
    }
    if (si < 3) WRITEQ((si + 1) & 1);
    __syncthreads();
  }

  // ---- Gram reduce: reuse P storage as Gw[8*16*65] ----
  float* Gw = &P[0][0];
#pragma unroll
  for (int p = 0; p < 13; ++p)
#pragma unroll
    for (int t = 0; t < 5; ++t) {
      float v = g[p][t];
      v += __shfl_xor(v, 16, 64);
      v += __shfl_xor(v, 32, 64);
      g[p][t] = v;
    }
  if (lane < 16) {
#pragma unroll
    for (int p = 0; p < 13; ++p)
#pragma unroll
      for (int t = 0; t < 5; ++t) Gw[((size_t)wv * 16 + lane) * 65 + p * 5 + t] = g[p][t];
  }
  __syncthreads();
#pragma unroll
  for (int it = 0; it < 2; ++it) {
    int slot = tid + it * 512;
    if (slot < 16 * 65) {
      int sseg = slot / 65, i = slot - sseg * 65;
      float v = 0.f;
#pragma unroll
      for (int ww = 0; ww < 8; ++ww) v += Gw[((size_t)ww * 16 + sseg) * 65 + i];
      int pl = i / 5, ty = i - pl * 5;
      int px = sseg * 13 + pl;
      if (px < NPIX)
        Gpart[((size_t)b * 16 + sg) * (5 * GST) + ty * GST + px] = v;
    }
  }
}

// ---------------- K_gemm3: 32x32x16 barrier-free MFMA, 2-deep ping-pong (r13-verified loop) ----
__global__ __launch_bounds__(256, 3) void k_gemm3(
    const ushort* __restrict__ xt,
    const ushort* __restrict__ cbf,
    const float* __restrict__ Gpart,   // [32][16][5*GST] partials (reduced inline)
    const float* __restrict__ csq,
    float* __restrict__ attn_out,
    float* __restrict__ part)
{
  __shared__ float RDs[128 * RDST];      // 34.8 KB
  __shared__ ushort Ssb[KDIM * SSTB];    // 13.6 KB
  __shared__ float csq_s[KDIM];
  __shared__ float xsqs[BNC], projs2[BNC];

  const int tid = threadIdx.x;
  const int wgid = blockIdx.x;
  const int xcd = wgid & 7, slot = wgid >> 3;
  const int bq = slot / NBX, bx = slot - bq * NBX;
  const int b = xcd + 8 * bq;
  const int n0 = bx * BNC;
  const int lane = tid & 63, w = tid >> 6;   // wave w = k-rows 32w..32w+31

  int r0 = bx - 1; if (r0 < 0) r0 = 0; if (r0 > 11) r0 = 11;
  const int T0 = r0 >> 1;                    // window = px' tiles T0, T0+1

  if (tid < KDIM) csq_s[tid] = csq[tid];

  const ushort* abp = cbf + w * 1024 + lane * 8;                    // + s*4096 + it*512
  const ushort* xtb = xt + (((size_t)b * 7 + T0) << 16) + lane * 8; // + tt*65536 + s*1024 + it*512

  f32x16 acc[2];
#pragma unroll
  for (int tt = 0; tt < 2; ++tt)
#pragma unroll
    for (int r = 0; r < 16; ++r) acc[tt][r] = 0.f;

#define LOADSET(A_, B_, S_)                                              \
  do {                                                                   \
    const size_t so_ = (size_t)(S_) * 4096;                              \
    const size_t xo_ = (size_t)(S_) * 1024;                              \
    A_[0] = *(const uint4*)(abp + so_);                                  \
    A_[1] = *(const uint4*)(abp + so_ + 512);                            \
    B_[0][0] = *(const uint4*)(xtb + xo_);                               \
    B_[0][1] = *(const uint4*)(xtb + xo_ + 512);                         \
    B_[1][0] = *(const uint4*)(xtb + 65536 + xo_);                       \
    B_[1][1] = *(const uint4*)(xtb + 65536 + xo_ + 512);                 \
  } while (0)

#define COMPUTE(A_, B_)                                                  \
  do {                                                                   \
    _Pragma("unroll")                                                    \
    for (int it_ = 0; it_ < 2; ++it_) {                                  \
      short8 af_ = *(const short8*)&A_[it_];                             \
      acc[0] = __builtin_amdgcn_mfma_f32_32x32x16_bf16(                  \
          af_, *(const short8*)&B_[0][it_], acc[0], 0, 0, 0);            \
      acc[1] = __builtin_amdgcn_mfma_f32_32x32x16_bf16(                  \
          af_, *(const short8*)&B_[1][it_], acc[1], 0, 0, 0);            \
    }                                                                    \
  } while (0)

  uint4 a0[2], a1[2], b0[2][2], b1[2][2];
  LOADSET(a0, b0, 0);
  for (int s = 0; s < NSTEP; s += 2) {
    if (s + 1 < NSTEP) LOADSET(a1, b1, s + 1);
    COMPUTE(a0, b0);
    if (s + 2 < NSTEP) LOADSET(a0, b0, s + 2);
    COMPUTE(a1, b1);
  }
#undef LOADSET
#undef COMPUTE

  // ---- RDs: 32x32 C/D layout col=lane&31, row=(r&3)+8*(r>>2)+4*(lane>>5) ----
#pragma unroll
  for (int tt = 0; tt < 2; ++tt)
#pragma unroll
    for (int r = 0; r < 16; ++r) {
      int row = w * 32 + (r & 3) + 8 * (r >> 2) + 4 * (lane >> 5);
      RDs[row * RDST + tt * 32 + (lane & 31)] = acc[tt][r];
    }
  __syncthreads();

  auto COLW = [&](int col, int& p1, int& p3, int& p1g, int& p3g,
                  float& w00, float& w01, float& w10, float& w11) {
    const int i2 = 2 * bx + (col >= 28 ? 1 : 0);
    const int j2 = col - (col >= 28 ? 28 : 0);
    float si = 0.5f * i2 - 0.25f, sj = 0.5f * j2 - 0.25f;
    float fif = floorf(si), fjf = floorf(sj);
    int ii = (int)fif, jj = (int)fjf;
    float fi = si - fif, fj = sj - fjf;
    int ia = ii < 0 ? 0 : ii; int ib = (ii + 1 > 13) ? 13 : ii + 1;
    int ja = jj < 0 ? 0 : jj; int jb = (jj + 1 > 13) ? 13 : jj + 1;
    w00 = (1.f - fi) * (1.f - fj); w01 = (1.f - fi) * fj;
    w10 = fi * (1.f - fj);         w11 = fi * fj;
    if (ib == ia) { w00 += w10; w01 += w11; w10 = 0.f; w11 = 0.f; }
    if (jb == ja) { w00 += w01; w10 += w11; w01 = 0.f; w11 = 0.f; }
    p1g = ia * HIN + ja; p3g = ib * HIN + ja;
    p1 = ia * 16 + ja - T0 * 32; p3 = ib * 16 + ja - T0 * 32;
  };

  // ---- xsq (Gram blend, inline 16-partial reduce) + raw proj ----
  if (tid < BNC) {
    int p1, p3, p1g, p3g; float w00, w01, w10, w11;
    COLW(tid, p1, p3, p1g, p3g, w00, w01, w10, w11);
    const float* Gp = Gpart + (size_t)b * 16 * (5 * GST);
    auto GS = [&](int ty, int px) {
      float v = 0.f;
#pragma unroll
      for (int sg = 0; sg < 16; ++sg) v += Gp[(size_t)sg * (5 * GST) + ty * GST + px];
      return v;
    };
    float xsq = w00 * w00 * GS(0, p1g) + w01 * w01 * GS(0, p1g + 1)
              + w10 * w10 * GS(0, p3g) + w11 * w11 * GS(0, p3g + 1)
              + 2.f * (w00 * w01 * GS(1, p1g) + w10 * w11 * GS(1, p3g)
                     + w00 * w10 * GS(3, p1g) + w01 * w11 * GS(3, p1g + 1)
                     + w00 * w11 * GS(4, p1g) + w01 * w10 * GS(2, p1g + 1));
    const float* rp = &RDs[113 * RDST];
    float pj = w00 * rp[p1] + w01 * rp[p1 + 1] + w10 * rp[p3] + w11 * rp[p3 + 1];
    xsqs[tid] = xsq; projs2[tid] = pj;
  }
  __syncthreads();

  // ---- dist (regs) -> quad softmax -> attn write (local rinv) + Ssb ----
  if (tid < BNC * 4) {
    const int col = tid >> 2, sub = tid & 3;
    int p1, p3, p1g, p3g; float w00, w01, w10, w11;
    COLW(col, p1, p3, p1g, p3g, w00, w01, w10, w11);
    const float xq = xsqs[col];
    float ev[29];
    float mx = -1e30f;
#pragma unroll
    for (int i = 0; i < 29; ++i) {
      int k = sub + 4 * i;
      if (k < KDIM) {
        const float* rk = &RDs[k * RDST];
        float dot = w00 * rk[p1] + w01 * rk[p1 + 1] + w10 * rk[p3] + w11 * rk[p3 + 1];
        float d2 = csq_s[k] + xq - 2.f * dot;
        float sv = -sqrtf(fmaxf(d2, 0.f));
        ev[i] = sv;
        mx = fmaxf(mx, sv);
      }
    }
    mx = fmaxf(mx, __shfl_xor(mx, 1, 64));
    mx = fmaxf(mx, __shfl_xor(mx, 2, 64));
    float ssum = 0.f;
#pragma unroll
    for (int i = 0; i < 29; ++i) {
      int k = sub + 4 * i;
      if (k < KDIM) {
        float e = __expf(ev[i] - mx);
        ev[i] = e;
        Ssb[k * SSTB + col] = __bfloat16_as_ushort(__float2bfloat16(e));
        ssum += e;
      }
    }
    ssum += __shfl_xor(ssum, 1, 64);
    ssum += __shfl_xor(ssum, 2, 64);
    const float rinv = 1.f / ssum;
    float* op = attn_out + (size_t)b * KDIM * N2 + n0 + col;
#pragma unroll
    for (int i = 0; i < 29; ++i) {
      int k = sub + 4 * i;
      if (k < KDIM) op[(size_t)k * N2] = ev[i] * rinv;
    }
    if (sub == 0) projs2[col] *= rinv;
  }
  __syncthreads();   // uniform barrier

  // ---- logit partials ----
  if (tid < KC * 2) {
    const int k = tid >> 1, s2 = tid & 1;
    float lg = 0.f;
    for (int c2 = s2; c2 < BNC; c2 += 2)
      lg = fmaf(__uint_as_float((uint)Ssb[k * SSTB + c2] << 16), projs2[c2], lg);
    lg += __shfl_xor(lg, 1, 64);
    if (s2 == 0) part[((size_t)b * NBX + bx) * KC + k] = lg;
  }
}

// ---------------- K_tmp (+sig fused) ----------------
__global__ __launch_bounds__(256) void k_tmp(
    const float* __restrict__ concepts, const float* __restrict__ part,
    const float* __restrict__ cfcb, float* __restrict__ cs_out,
    float* __restrict__ tmp) {
  __shared__ float cs_s[KC];
  const int b = blockIdx.y, cx = blockIdx.x;
  const int t = threadIdx.x;
  if (t < KC) {
    float l = cfcb[0];
#pragma unroll
    for (int q = 0; q < NBX; ++q) l += part[((size_t)b * NBX + q) * KC + t];
    float csv = 1.f / (1.f + __expf(-l));
    cs_s[t] = csv;
    if (cx == 0) cs_out[b * KC + t] = csv;
  }
  __syncthreads();
  const int c = cx * 256 + t;
  float a = 0.f;
#pragma unroll 8
  for (int k = 0; k < KC; ++k) a = fmaf(cs_s[k], concepts[(size_t)k * CDIM + c], a);
  tmp[(size_t)b * CDIM + c] = a;
}

// ---------------- K5b: preds ----------------
__global__ __launch_bounds__(256) void k_pred2(
    const float* __restrict__ labw, const float* __restrict__ labb,
    const float* __restrict__ tmp, float* __restrict__ preds) {
  const int w = blockIdx.x * 4 + (threadIdx.x >> 6);
  const int lane = threadIdx.x & 63;
  const int b = w / NCLS, cls = w % NCLS;
  if (b >= BDIM) return;
  const float* tr = tmp + (size_t)b * CDIM;
  const float* wr = labw + (size_t)cls * CDIM;
  float a = 0.f;
#pragma unroll
  for (int c0 = 0; c0 < CDIM; c0 += 256) {
    float4 t = *(const float4*)&tr[c0 + lane * 4];
    float4 v = *(const float4*)&wr[c0 + lane * 4];
    a += t.x * v.x + t.y * v.y + t.z * v.z + t.w * v.w;
  }
#pragma unroll
  for (int off = 32; off > 0; off >>= 1) a += __shfl_down(a, off, 64);
  if (lane == 0) preds[b * NCLS + cls] = a + labb[cls];
}

extern "C" void kernel_launch(void* const* d_in, const int* in_sizes, int n_in,
                              void* d_out, int out_size, void* d_ws, size_t ws_size,
                              hipStream_t stream) {
  const float* x        = (const float*)d_in[0];
  const float* concepts = (const float*)d_in[1];
  const float* cfcw     = (const float*)d_in[2];
  const float* cfcb     = (const float*)d_in[3];
  const float* labw     = (const float*)d_in[4];
  const float* labb     = (const float*)d_in[5];

  float* out    = (float*)d_out;
  float* sm_out = out;                                  // [32][113][784]
  float* cs_out = out + (size_t)BDIM * KDIM * N2;       // [32][112]
  float* pr_out = cs_out + (size_t)BDIM * KC;           // [32][200]

  char* ws = (char*)d_ws;
  float*  csq   = (float*)(ws + 0);          // 128 f32             512 B
  float*  part  = (float*)(ws + 512);        // 32*14*112 f32       200,704 B
  ushort* cbf   = (ushort*)(ws + 201216);    // 128*2048 bf16       524,288 B
  float*  tmp   = (float*)(ws + 725504);     // 32*2048 f32         262,144 B
  float*  Gpart = (float*)(ws + 987648);     // 32*16*1000 f32      2,048,000 B
  ushort* xt    = (ushort*)(ws + 3163648);   // 32*7*64*1024 bf16   29,360,128 B

  k_stage<<<dim3(640), dim3(512), 0, stream>>>(x, concepts, cfcw, cbf, csq, xt, Gpart);
  k_gemm3<<<dim3(448), dim3(256), 0, stream>>>(xt, cbf, Gpart, csq, sm_out, part);
  k_tmp  <<<dim3(CDIM / 256, BDIM), dim3(256), 0, stream>>>(concepts, part, cfcb, cs_out, tmp);
  k_pred2<<<dim3((BDIM * NCLS + 3) / 4), dim3(256), 0, stream>>>(labw, labb, tmp, pr_out);
}